// Round 13
// baseline (88.306 us; speedup 1.0000x reference)
//
#include <hip/hip_runtime.h>
#include <hip/hip_bf16.h>
#include <math.h>

#define C_DIM 512
#define H_DIM 1024
#define NTOK  2048
#define NSLOT 4096
#define NROWS 6144
#define MAXTE 48          // expert tiles (128-row): <=32 full + <=16 partial

typedef __attribute__((ext_vector_type(8))) short short8;
typedef __attribute__((ext_vector_type(4))) float floatx4;
typedef __attribute__((address_space(3))) void as3_void;
typedef const __attribute__((address_space(1))) void as1_cvoid;

__device__ __forceinline__ void gload_lds16(const void* g, void* l){
  __builtin_amdgcn_global_load_lds((as1_cvoid*)g, (as3_void*)l, 16, 0, 0);
}

__device__ __forceinline__ unsigned short f2b(float f){
  unsigned int u = __float_as_uint(f);
  unsigned int r = (u + 0x7FFFu + ((u >> 16) & 1u)) >> 16;
  return (unsigned short)r;
}

// ---- transpose tile (256 thr): f32 [K][N] -> bf16 [N][K], 128k x 64n ----
__device__ __forceinline__ void transpose_tile(const float* __restrict__ in,
                                               unsigned short* __restrict__ out,
                                               int K, int N, int n0, int k0,
                                               int tid, float* tile){
  int tx = tid & 15, ty = tid >> 4;
  #pragma unroll
  for (int i = 0; i < 8; i++){
    int k = ty + 16 * i;
    float4 v = *reinterpret_cast<const float4*>(in + (size_t)(k0 + k) * N + n0 + tx * 4);
    tile[(4*tx + 0) * 129 + k] = v.x;
    tile[(4*tx + 1) * 129 + k] = v.y;
    tile[(4*tx + 2) * 129 + k] = v.z;
    tile[(4*tx + 3) * 129 + k] = v.w;
  }
  __syncthreads();
  int wt = tid & 31, wr = tid >> 5;
  #pragma unroll
  for (int i = 0; i < 8; i++){
    int n = wr + 8 * i;
    float4 v = *reinterpret_cast<const float4*>(&tile[n * 129 + 4 * wt]);
    ushort4 o;
    o.x = f2b(v.x); o.y = f2b(v.y); o.z = f2b(v.z); o.w = f2b(v.w);
    *reinterpret_cast<ushort4*>(out + (size_t)(n0 + n) * K + k0 + 4 * wt) = o;
  }
}

// ---- GEMM tile body: 128x128, BK=64, 4 waves, single-buffered LDS (32 KB) ----
// As/Bs layouts identical to R10 (pre-swizzled source, XOR ds_read).
template<bool GATHER, bool RELU, bool OUTBF, bool WEIGHTED, int KDIM, int NDIM>
__device__ __forceinline__ void gemm_tile(const unsigned short* __restrict__ A,
                                          const unsigned short* __restrict__ Bt,
                                          const float* __restrict__ bias,
                                          const int* __restrict__ rowTok,
                                          const float* __restrict__ rowW,
                                          int row0, int rows, int n0,
                                          int tid, char* smem,
                                          unsigned short* __restrict__ outB,
                                          float* __restrict__ outF){
  char* As = smem;            // 16 KB
  char* Bs = smem + 16384;    // 16 KB
  const int lane = tid & 63;
  const int wid = tid >> 6;
  const int wm = wid >> 1, wn = wid & 1;
  const int l15 = lane & 15, lhi = lane >> 4;

  int aRow[4], aOff[4], bRow[4], bOff[4];
  #pragma unroll
  for (int j = 0; j < 4; j++){
    int c = j * 256 + tid;
    int i = c >> 3, op = c & 7;
    int o = op ^ (i & 7);
    int ie = min(i, rows - 1);
    aRow[j] = GATHER ? rowTok[row0 + ie] : (row0 + ie);
    aOff[j] = o * 8;
    bRow[j] = n0 + i;
    bOff[j] = o * 8;
  }

  floatx4 acc[4][4] = {};
  for (int kt = 0; kt < KDIM / 64; ++kt){
    #pragma unroll
    for (int j = 0; j < 4; j++)
      gload_lds16(A + (size_t)aRow[j] * KDIM + kt * 64 + aOff[j],
                  As + (j * 256 + tid) * 16);
    #pragma unroll
    for (int j = 0; j < 4; j++)
      gload_lds16(Bt + (size_t)bRow[j] * KDIM + kt * 64 + bOff[j],
                  Bs + (j * 256 + tid) * 16);
    __syncthreads();
    #pragma unroll
    for (int kk = 0; kk < 2; ++kk){
      short8 a[4], b[4];
      #pragma unroll
      for (int m = 0; m < 4; m++){
        int rr = wm * 64 + m * 16 + l15;
        a[m] = *reinterpret_cast<const short8*>(
            As + rr * 128 + ((kk * 64 + lhi * 16) ^ ((rr & 7) << 4)));
      }
      #pragma unroll
      for (int n = 0; n < 4; n++){
        int rr = wn * 64 + n * 16 + l15;
        b[n] = *reinterpret_cast<const short8*>(
            Bs + rr * 128 + ((kk * 64 + lhi * 16) ^ ((rr & 7) << 4)));
      }
      #pragma unroll
      for (int m = 0; m < 4; m++)
        #pragma unroll
        for (int n = 0; n < 4; n++)
          acc[m][n] = __builtin_amdgcn_mfma_f32_16x16x32_bf16(a[m], b[n], acc[m][n], 0, 0, 0);
    }
    __syncthreads();
  }

  #pragma unroll
  for (int m = 0; m < 4; m++){
    #pragma unroll
    for (int n = 0; n < 4; n++){
      int gcol = n0 + wn * 64 + n * 16 + l15;
      float bv = bias[gcol];
      #pragma unroll
      for (int q = 0; q < 4; q++){
        int ri = wm * 64 + m * 16 + lhi * 4 + q;
        if (ri < rows){
          float v = acc[m][n][q] + bv;
          if constexpr (OUTBF){
            if (RELU) v = fmaxf(v, 0.f);
            outB[(size_t)(row0 + ri) * NDIM + gcol] = f2b(v);
          } else {
            if constexpr (WEIGHTED) v *= rowW[row0 + ri];
            outF[(size_t)(row0 + ri) * NDIM + gcol] = v;
          }
        }
      }
    }
  }
}

// ===== K1: router+cvt (bid<512) + W1 transposes (512..1599) =====
__global__ __launch_bounds__(256) void k_prep(const float* __restrict__ x,
                                              const int* __restrict__ op_id,
                                              const float* __restrict__ ekey,
                                              const float* __restrict__ sW1,
                                              const float* __restrict__ eW1,
                                              unsigned short* __restrict__ Xb,
                                              unsigned short* __restrict__ sW1t,
                                              unsigned short* __restrict__ eW1t,
                                              int* __restrict__ gids,
                                              float* __restrict__ wv){
  __shared__ __align__(16) float tile[64 * 129];
  const int bid = blockIdx.x;
  const int tid = threadIdx.x;

  if (bid >= 512){
    int tb = bid - 512;
    int mat = tb >> 6, tl = tb & 63;
    const float* in  = (mat < 16) ? eW1 + (size_t)mat * C_DIM * H_DIM : sW1;
    unsigned short* out = (mat < 16) ? eW1t + (size_t)mat * C_DIM * H_DIM : sW1t;
    transpose_tile(in, out, C_DIM, H_DIM, (tl & 15) * 64, (tl >> 4) * 128, tid, tile);
    return;
  }
  int t = bid * 4 + (tid >> 6);
  int lane = tid & 63;
  const float* xr = x + (size_t)t * C_DIM;
  {
    const float4* xr4 = reinterpret_cast<const float4*>(xr);
    float4 a = xr4[lane * 2], b = xr4[lane * 2 + 1];
    short8 o;
    o[0] = (short)f2b(a.x); o[1] = (short)f2b(a.y); o[2] = (short)f2b(a.z); o[3] = (short)f2b(a.w);
    o[4] = (short)f2b(b.x); o[5] = (short)f2b(b.y); o[6] = (short)f2b(b.z); o[7] = (short)f2b(b.w);
    *reinterpret_cast<short8*>(Xb + (size_t)t * C_DIM + lane * 8) = o;
  }
  float xs[8];
  float xn2 = 0.f;
  #pragma unroll
  for (int i = 0; i < 8; i++){ float v = xr[lane + 64*i]; xs[i] = v; xn2 += v*v; }
  #pragma unroll
  for (int o = 32; o; o >>= 1) xn2 += __shfl_xor(xn2, o, 64);
  int bucket = min(max(op_id[t], 0), 3);
  float xn = fmaxf(sqrtf(xn2), 1e-12f);
  float pr[4];
  #pragma unroll
  for (int e = 0; e < 4; e++){
    const float* kr = ekey + ((size_t)bucket * 4 + e) * C_DIM;
    float dot = 0.f, kn2 = 0.f;
    #pragma unroll
    for (int i = 0; i < 8; i++){ float kv = kr[lane + 64*i]; dot += xs[i]*kv; kn2 += kv*kv; }
    #pragma unroll
    for (int o = 32; o; o >>= 1){ dot += __shfl_xor(dot, o, 64); kn2 += __shfl_xor(kn2, o, 64); }
    float kn = fmaxf(sqrtf(kn2), 1e-12f);
    pr[e] = dot / (xn * kn);
  }
  float mx = fmaxf(fmaxf(pr[0], pr[1]), fmaxf(pr[2], pr[3]));
  float Z = 0.f;
  #pragma unroll
  for (int e = 0; e < 4; e++){ pr[e] = expf(pr[e] - mx); Z += pr[e]; }
  #pragma unroll
  for (int e = 0; e < 4; e++) pr[e] /= Z;
  int i0 = 0;
  #pragma unroll
  for (int e = 1; e < 4; e++) if (pr[e] > pr[i0]) i0 = e;
  int i1 = (i0 == 0) ? 1 : 0;
  #pragma unroll
  for (int e = 0; e < 4; e++) if (e != i0 && e != i1 && pr[e] > pr[i1]) i1 = e;
  float v0 = pr[i0], v1 = pr[i1];
  float wsum = v0 + v1 + 1e-9f;
  if (lane == 0){
    gids[2*t]   = bucket * 4 + i0;
    gids[2*t+1] = bucket * 4 + i1;
    wv[2*t]   = v0 / wsum;
    wv[2*t+1] = v1 / wsum;
  }
}

// ===== K2: sort (bid 0) + GEMM1-dense (bid 1..128) + W2 transposes (129..1216) =====
__global__ __launch_bounds__(256) void k_sg1d(const int* __restrict__ gids,
                                              const float* __restrict__ wv,
                                              const float* __restrict__ gate,
                                              int* __restrict__ inv,
                                              int* __restrict__ rowTok,
                                              float* __restrict__ rowW,
                                              int* __restrict__ tilesE,
                                              const unsigned short* __restrict__ Xb,
                                              const unsigned short* __restrict__ sW1t,
                                              const float* __restrict__ sb1,
                                              unsigned short* __restrict__ H1,
                                              const float* __restrict__ sW2,
                                              const float* __restrict__ eW2,
                                              unsigned short* __restrict__ sW2t,
                                              unsigned short* __restrict__ eW2t){
  __shared__ __align__(16) char smem[33024];
  const int bid = blockIdx.x;
  const int tid = threadIdx.x;

  if (bid == 0){
    int (*hist)[16] = (int(*)[16])smem;
    int* off = (int*)(smem + 16384);
    float sig = 1.f / (1.f + expf(-gate[0]));
    int h[16], g_[16];
    #pragma unroll
    for (int e = 0; e < 16; e++) h[e] = 0;
    int base = tid * 16;
    #pragma unroll
    for (int s = 0; s < 16; s++){ g_[s] = gids[base + s]; h[g_[s]]++; }
    #pragma unroll
    for (int e = 0; e < 16; e++) hist[tid][e] = h[e];
    __syncthreads();
    for (int d = 1; d < 256; d <<= 1){
      int v[16];
      if (tid >= d){
        #pragma unroll
        for (int e = 0; e < 16; e++) v[e] = hist[tid - d][e];
      }
      __syncthreads();
      if (tid >= d){
        #pragma unroll
        for (int e = 0; e < 16; e++) hist[tid][e] += v[e];
      }
      __syncthreads();
    }
    if (tid == 0){
      off[0] = 0;
      for (int e = 0; e < 16; e++) off[e+1] = off[e] + hist[255][e];
    }
    __syncthreads();
    int c[16];
    #pragma unroll
    for (int e = 0; e < 16; e++) c[e] = off[e] + hist[tid][e] - h[e];
    #pragma unroll
    for (int s = 0; s < 16; s++){
      int slot = base + s;
      int g = g_[s];
      int pos = c[g]++;
      inv[slot] = pos;
      rowTok[NTOK + pos] = slot >> 1;
      rowW[NTOK + pos] = sig * wv[slot];
    }
    __syncthreads();
    if (tid == 0){
      int nt = 0;
      for (int e = 0; e < 16; e++){
        int cc = off[e+1] - off[e];
        for (int r0 = 0; r0 < cc; r0 += 128){
          tilesE[nt*3] = NTOK + off[e] + r0;
          tilesE[nt*3+1] = min(128, cc - r0);
          tilesE[nt*3+2] = e;
          nt++;
        }
      }
      for (int i = nt; i < MAXTE; i++){ tilesE[i*3] = 0; tilesE[i*3+1] = 0; tilesE[i*3+2] = 0; }
    }
    return;
  }
  if (bid <= 128){
    // GEMM1-dense: static tiles, identity rows, shared weights
    int g = bid - 1;
    gemm_tile<false, true, true, false, C_DIM, H_DIM>(
        Xb, sW1t, sb1, nullptr, nullptr,
        (g >> 3) * 128, 128, (g & 7) * 128, tid, smem, H1, nullptr);
    return;
  }
  int tb = bid - 129;
  int mat = tb >> 6, tl = tb & 63;
  const float* in  = (mat < 16) ? eW2 + (size_t)mat * H_DIM * C_DIM : sW2;
  unsigned short* out = (mat < 16) ? eW2t + (size_t)mat * H_DIM * C_DIM : sW2t;
  transpose_tile(in, out, H_DIM, C_DIM, (tl & 7) * 64, (tl >> 3) * 128, tid, (float*)smem);
}

// ===== K3: GEMM1-expert (bid<384) + GEMM2-dense (384..447) =====
__global__ __launch_bounds__(256) void k_g1e_g2d(const unsigned short* __restrict__ Xb,
                                                 const unsigned short* __restrict__ eW1t,
                                                 const float* __restrict__ eb1,
                                                 const int* __restrict__ rowTok,
                                                 const int* __restrict__ tilesE,
                                                 unsigned short* __restrict__ H1,
                                                 const unsigned short* __restrict__ sW2t,
                                                 const float* __restrict__ sb2,
                                                 float* __restrict__ O){
  __shared__ __align__(16) char smem[33024];
  const int bid = blockIdx.x;
  const int tid = threadIdx.x;

  if (bid < MAXTE * 8){
    const int tileId = bid >> 3;
    const int rows = tilesE[tileId*3+1];
    if (rows == 0) return;
    const int row0 = tilesE[tileId*3];
    const int eid  = tilesE[tileId*3+2];
    gemm_tile<true, true, true, false, C_DIM, H_DIM>(
        Xb, eW1t + (size_t)eid * H_DIM * C_DIM, eb1 + eid * H_DIM, rowTok, nullptr,
        row0, rows, (bid & 7) * 128, tid, smem, H1, nullptr);
    return;
  }
  // GEMM2-dense: 16 tiles x 4 n-blocks over N=512
  int g = bid - MAXTE * 8;
  gemm_tile<false, false, false, false, H_DIM, C_DIM>(
      H1, sW2t, sb2, nullptr, nullptr,
      (g >> 2) * 128, 128, (g & 3) * 128, tid, smem, nullptr, O);
}

// ===== K4: GEMM2-expert (192 blocks) =====
__global__ __launch_bounds__(256) void k_g2e(const unsigned short* __restrict__ H1,
                                             const unsigned short* __restrict__ eW2t,
                                             const float* __restrict__ eb2,
                                             const float* __restrict__ rowW,
                                             const int* __restrict__ tilesE,
                                             float* __restrict__ O){
  __shared__ __align__(16) char smem[33024];
  const int bid = blockIdx.x;
  const int tid = threadIdx.x;
  const int tileId = bid >> 2;
  const int rows = tilesE[tileId*3+1];
  if (rows == 0) return;
  const int row0 = tilesE[tileId*3];
  const int eid  = tilesE[tileId*3+2];
  gemm_tile<false, false, false, true, H_DIM, C_DIM>(
      H1, eW2t + (size_t)eid * C_DIM * H_DIM, eb2 + eid * C_DIM, nullptr, rowW,
      row0, rows, (bid & 3) * 128, tid, smem, nullptr, O);
}

// ===== K5: combine y = O_dense + O_e0 + O_e1 (weights folded) =====
__global__ __launch_bounds__(256) void k_combine(const float* __restrict__ O,
                                                 const int* __restrict__ inv,
                                                 float* __restrict__ y){
  int q = blockIdx.x * 256 + threadIdx.x;
  int t = q >> 7, c4 = q & 127;
  const float4* Of = reinterpret_cast<const float4*>(O);
  float4 d  = Of[(size_t)t * 128 + c4];
  int p0 = inv[2*t], p1 = inv[2*t+1];
  float4 o0 = Of[(size_t)(NTOK + p0) * 128 + c4];
  float4 o1 = Of[(size_t)(NTOK + p1) * 128 + c4];
  float4 r;
  r.x = d.x + o0.x + o1.x;
  r.y = d.y + o0.y + o1.y;
  r.z = d.z + o0.z + o1.z;
  r.w = d.w + o0.w + o1.w;
  reinterpret_cast<float4*>(y)[q] = r;
}

extern "C" void kernel_launch(void* const* d_in, const int* in_sizes, int n_in,
                              void* d_out, int out_size, void* d_ws, size_t ws_size,
                              hipStream_t stream){
  const float* x    = (const float*)d_in[0];
  const int*   opid = (const int*)d_in[1];
  const float* ekey = (const float*)d_in[2];
  const float* sW1  = (const float*)d_in[3];
  const float* sb1  = (const float*)d_in[4];
  const float* sW2  = (const float*)d_in[5];
  const float* sb2  = (const float*)d_in[6];
  const float* eW1  = (const float*)d_in[7];
  const float* eb1  = (const float*)d_in[8];
  const float* eW2  = (const float*)d_in[9];
  const float* eb2  = (const float*)d_in[10];
  const float* gate = (const float*)d_in[11];
  float* y = (float*)d_out;

  char* ws = (char*)d_ws;
  size_t off = 0;
  auto alloc = [&](size_t bytes) -> char* {
    char* p = ws + off; off += (bytes + 255) & ~(size_t)255; return p;
  };
  unsigned short* Xb   = (unsigned short*)alloc((size_t)NTOK * C_DIM * 2);
  unsigned short* sW1t = (unsigned short*)alloc((size_t)H_DIM * C_DIM * 2);
  unsigned short* sW2t = (unsigned short*)alloc((size_t)C_DIM * H_DIM * 2);
  unsigned short* eW1t = (unsigned short*)alloc((size_t)16 * H_DIM * C_DIM * 2);
  unsigned short* eW2t = (unsigned short*)alloc((size_t)16 * C_DIM * H_DIM * 2);
  unsigned short* H1   = (unsigned short*)alloc((size_t)NROWS * H_DIM * 2);
  float* O      = (float*)alloc((size_t)NROWS * C_DIM * 4);
  float* wv     = (float*)alloc((size_t)NSLOT * 4);
  int*   gids   = (int*)alloc((size_t)NSLOT * 4);
  int*   inv    = (int*)alloc((size_t)NSLOT * 4);
  int*   rowTok = (int*)alloc((size_t)NROWS * 4);
  float* rowW   = (float*)alloc((size_t)NROWS * 4);
  int*   tilesE = (int*)alloc((size_t)MAXTE * 3 * 4);

  k_prep<<<1600, 256, 0, stream>>>(x, opid, ekey, sW1, eW1, Xb, sW1t, eW1t, gids, wv);
  k_sg1d<<<1 + 128 + 1088, 256, 0, stream>>>(gids, wv, gate, inv, rowTok, rowW, tilesE,
                                             Xb, sW1t, sb1, H1, sW2, eW2, sW2t, eW2t);
  k_g1e_g2d<<<MAXTE * 8 + 64, 256, 0, stream>>>(Xb, eW1t, eb1, rowTok, tilesE, H1,
                                                sW2t, sb2, O);
  k_g2e<<<MAXTE * 4, 256, 0, stream>>>(H1, eW2t, eb2, rowW, tilesE, O);
  k_combine<<<1024, 256, 0, stream>>>(O, inv, y);
}

// Round 14
// 78.486 us; speedup vs baseline: 1.1251x; 1.1251x over previous
//
#include <hip/hip_runtime.h>
#include <hip/hip_bf16.h>
#include <math.h>

#define C_DIM 512
#define H_DIM 1024
#define NTOK  2048
#define NSLOT 4096
#define NROWS 6144
#define MAXT128 64
#define MAXT64  112
#define NBG1 512

typedef __attribute__((ext_vector_type(8))) short short8;
typedef __attribute__((ext_vector_type(4))) float floatx4;
typedef __attribute__((address_space(3))) void as3_void;
typedef const __attribute__((address_space(1))) void as1_cvoid;

__device__ __forceinline__ void gload_lds16(const void* g, void* l){
  __builtin_amdgcn_global_load_lds((as1_cvoid*)g, (as3_void*)l, 16, 0, 0);
}

__device__ __forceinline__ unsigned short f2b(float f){
  unsigned int u = __float_as_uint(f);
  unsigned int r = (u + 0x7FFFu + ((u >> 16) & 1u)) >> 16;
  return (unsigned short)r;
}
__device__ __forceinline__ float b2f(unsigned short s){
  return __uint_as_float(((unsigned int)s) << 16);
}

// ---- transpose tile: f32 [K][N] -> bf16 [N][K], 128k x 64n (33024 B LDS) ----
__device__ __forceinline__ void transpose_tile(const float* __restrict__ in,
                                               unsigned short* __restrict__ out,
                                               int K, int N, int n0, int k0,
                                               int tid, float* tile){
  int tx = tid & 15, ty = tid >> 4;
  #pragma unroll
  for (int i = 0; i < 8; i++){
    int k = ty + 16 * i;
    float4 v = *reinterpret_cast<const float4*>(in + (size_t)(k0 + k) * N + n0 + tx * 4);
    tile[(4*tx + 0) * 129 + k] = v.x;
    tile[(4*tx + 1) * 129 + k] = v.y;
    tile[(4*tx + 2) * 129 + k] = v.z;
    tile[(4*tx + 3) * 129 + k] = v.w;
  }
  __syncthreads();
  int wt = tid & 31, wr = tid >> 5;
  #pragma unroll
  for (int i = 0; i < 8; i++){
    int n = wr + 8 * i;
    float4 v = *reinterpret_cast<const float4*>(&tile[n * 129 + 4 * wt]);
    ushort4 o;
    o.x = f2b(v.x); o.y = f2b(v.y); o.z = f2b(v.z); o.w = f2b(v.w);
    *reinterpret_cast<ushort4*>(out + (size_t)(n0 + n) * K + k0 + 4 * wt) = o;
  }
}

// ===== K1: router + x->bf16 (512 blocks, 4 tokens each) =====
__global__ __launch_bounds__(256) void k_router(const float* __restrict__ x,
                                                const int* __restrict__ op_id,
                                                const float* __restrict__ ekey,
                                                unsigned short* __restrict__ Xb,
                                                int* __restrict__ gids,
                                                float* __restrict__ wv){
  int t = blockIdx.x * 4 + (threadIdx.x >> 6);
  int lane = threadIdx.x & 63;
  const float* xr = x + (size_t)t * C_DIM;
  {
    const float4* xr4 = reinterpret_cast<const float4*>(xr);
    float4 a = xr4[lane * 2], b = xr4[lane * 2 + 1];
    short8 o;
    o[0] = (short)f2b(a.x); o[1] = (short)f2b(a.y); o[2] = (short)f2b(a.z); o[3] = (short)f2b(a.w);
    o[4] = (short)f2b(b.x); o[5] = (short)f2b(b.y); o[6] = (short)f2b(b.z); o[7] = (short)f2b(b.w);
    *reinterpret_cast<short8*>(Xb + (size_t)t * C_DIM + lane * 8) = o;
  }
  float xs[8];
  float xn2 = 0.f;
  #pragma unroll
  for (int i = 0; i < 8; i++){ float v = xr[lane + 64*i]; xs[i] = v; xn2 += v*v; }
  #pragma unroll
  for (int o = 32; o; o >>= 1) xn2 += __shfl_xor(xn2, o, 64);
  int bucket = min(max(op_id[t], 0), 3);
  float xn = fmaxf(sqrtf(xn2), 1e-12f);
  float pr[4];
  #pragma unroll
  for (int e = 0; e < 4; e++){
    const float* kr = ekey + ((size_t)bucket * 4 + e) * C_DIM;
    float dot = 0.f, kn2 = 0.f;
    #pragma unroll
    for (int i = 0; i < 8; i++){ float kv = kr[lane + 64*i]; dot += xs[i]*kv; kn2 += kv*kv; }
    #pragma unroll
    for (int o = 32; o; o >>= 1){ dot += __shfl_xor(dot, o, 64); kn2 += __shfl_xor(kn2, o, 64); }
    float kn = fmaxf(sqrtf(kn2), 1e-12f);
    pr[e] = dot / (xn * kn);
  }
  float mx = fmaxf(fmaxf(pr[0], pr[1]), fmaxf(pr[2], pr[3]));
  float Z = 0.f;
  #pragma unroll
  for (int e = 0; e < 4; e++){ pr[e] = expf(pr[e] - mx); Z += pr[e]; }
  #pragma unroll
  for (int e = 0; e < 4; e++) pr[e] /= Z;
  int i0 = 0;
  #pragma unroll
  for (int e = 1; e < 4; e++) if (pr[e] > pr[i0]) i0 = e;
  int i1 = (i0 == 0) ? 1 : 0;
  #pragma unroll
  for (int e = 0; e < 4; e++) if (e != i0 && e != i1 && pr[e] > pr[i1]) i1 = e;
  float v0 = pr[i0], v1 = pr[i1];
  float wsum = v0 + v1 + 1e-9f;
  if (lane == 0){
    gids[2*t]   = bucket * 4 + i0;
    gids[2*t+1] = bucket * 4 + i1;
    wv[2*t]   = v0 / wsum;
    wv[2*t+1] = v1 / wsum;
  }
}

// ===== K2: block 0 = counting sort (tree scan) + tables; blocks 1..1088 = W1 transposes =====
__global__ __launch_bounds__(256) void k_sortw1(const int* __restrict__ gids,
                                                const float* __restrict__ wv,
                                                const float* __restrict__ gate,
                                                const float* __restrict__ sW1,
                                                const float* __restrict__ eW1,
                                                unsigned short* __restrict__ sW1t,
                                                unsigned short* __restrict__ eW1t,
                                                int* __restrict__ inv,
                                                int* __restrict__ rowTok,
                                                float* __restrict__ rowW,
                                                int* __restrict__ tiles128,
                                                int* __restrict__ tiles64){
  __shared__ __align__(16) char smem[33280];
  const int bid = blockIdx.x;
  const int tid = threadIdx.x;

  if (bid == 0){
    int (*hist)[16] = (int(*)[16])smem;
    int* off = (int*)(smem + 16384);
    float sig = 1.f / (1.f + expf(-gate[0]));
    int h[16], g_[16];
    #pragma unroll
    for (int e = 0; e < 16; e++) h[e] = 0;
    int base = tid * 16;
    #pragma unroll
    for (int s = 0; s < 16; s++){ g_[s] = gids[base + s]; h[g_[s]]++; }
    #pragma unroll
    for (int e = 0; e < 16; e++) hist[tid][e] = h[e];
    __syncthreads();
    for (int d = 1; d < 256; d <<= 1){
      int v[16];
      if (tid >= d){
        #pragma unroll
        for (int e = 0; e < 16; e++) v[e] = hist[tid - d][e];
      }
      __syncthreads();
      if (tid >= d){
        #pragma unroll
        for (int e = 0; e < 16; e++) hist[tid][e] += v[e];
      }
      __syncthreads();
    }
    if (tid == 0){
      off[0] = 0;
      for (int e = 0; e < 16; e++) off[e+1] = off[e] + hist[255][e];
    }
    __syncthreads();
    int c[16];
    #pragma unroll
    for (int e = 0; e < 16; e++) c[e] = off[e] + hist[tid][e] - h[e];
    #pragma unroll
    for (int s = 0; s < 16; s++){
      int slot = base + s;
      int g = g_[s];
      int pos = c[g]++;
      inv[slot] = pos;
      rowTok[NTOK + pos] = slot >> 1;
      rowW[NTOK + pos] = sig * wv[slot];
    }
    for (int r = tid; r < NTOK; r += 256){ rowTok[r] = r; rowW[r] = 1.0f; }
    __syncthreads();
    if (tid == 0){
      int nt = 0;
      for (int r0 = 0; r0 < NTOK; r0 += 128){
        tiles128[nt*3] = r0; tiles128[nt*3+1] = 128; tiles128[nt*3+2] = 16; nt++;
      }
      for (int e = 0; e < 16; e++){
        int cc = off[e+1] - off[e];
        for (int r0 = 0; r0 < cc; r0 += 128){
          tiles128[nt*3] = NTOK + off[e] + r0;
          tiles128[nt*3+1] = min(128, cc - r0);
          tiles128[nt*3+2] = e;
          nt++;
        }
      }
      for (int i = nt; i < MAXT128; i++){ tiles128[i*3] = 0; tiles128[i*3+1] = 0; tiles128[i*3+2] = 0; }
      nt = 0;
      for (int r0 = 0; r0 < NTOK; r0 += 64){
        tiles64[nt*3] = r0; tiles64[nt*3+1] = 64; tiles64[nt*3+2] = 16; nt++;
      }
      for (int e = 0; e < 16; e++){
        int cc = off[e+1] - off[e];
        for (int r0 = 0; r0 < cc; r0 += 64){
          tiles64[nt*3] = NTOK + off[e] + r0;
          tiles64[nt*3+1] = min(64, cc - r0);
          tiles64[nt*3+2] = e;
          nt++;
        }
      }
      for (int i = nt; i < MAXT64; i++){ tiles64[i*3] = 0; tiles64[i*3+1] = 0; tiles64[i*3+2] = 0; }
    }
    return;
  }

  int tb = bid - 1;
  int mat = tb >> 6, tl = tb & 63;
  const float* in  = (mat < 16) ? eW1 + (size_t)mat * C_DIM * H_DIM : sW1;
  unsigned short* out = (mat < 16) ? eW1t + (size_t)mat * C_DIM * H_DIM : sW1t;
  transpose_tile(in, out, C_DIM, H_DIM, (tl & 15) * 64, (tl >> 4) * 128, tid, (float*)smem);
}

// ===== K3: GEMM1 (blocks 0..511, single-buffered 32KB) + W2 transposes (512..1599) =====
__global__ __launch_bounds__(256) void k_g1w2(const unsigned short* __restrict__ A,
                                              const unsigned short* __restrict__ BtE,
                                              const unsigned short* __restrict__ BtS,
                                              const float* __restrict__ biasE,
                                              const float* __restrict__ biasS,
                                              const int* __restrict__ rowTok,
                                              const int* __restrict__ tiles,
                                              unsigned short* __restrict__ outB,
                                              const float* __restrict__ sW2,
                                              const float* __restrict__ eW2,
                                              unsigned short* __restrict__ sW2t,
                                              unsigned short* __restrict__ eW2t){
  __shared__ __align__(16) char smem[33024];
  const int bx = blockIdx.x;
  const int tid = threadIdx.x;

  if (bx >= NBG1){
    int wi = bx - NBG1;
    int mat = wi >> 6, tl = wi & 63;
    const float* in  = (mat < 16) ? eW2 + (size_t)mat * H_DIM * C_DIM : sW2;
    unsigned short* out = (mat < 16) ? eW2t + (size_t)mat * H_DIM * C_DIM : sW2t;
    transpose_tile(in, out, H_DIM, C_DIM, (tl & 7) * 64, (tl >> 3) * 128, tid, (float*)smem);
    return;
  }

  constexpr int KDIM = C_DIM, NDIM = H_DIM;
  const int tileId = bx >> 3;
  const int rows = tiles[tileId*3+1];
  if (rows == 0) return;
  const int row0 = tiles[tileId*3];
  const int eid  = tiles[tileId*3+2];
  const unsigned short* Bt = (eid < 16) ? (BtE + (size_t)eid * NDIM * KDIM) : BtS;
  const float* bias = (eid < 16) ? (biasE + eid * NDIM) : biasS;
  const int n0 = (bx & 7) * 128;

  char* As = smem;
  char* Bs = smem + 16384;

  const int lane = tid & 63;
  const int wid = tid >> 6;
  const int wm = wid >> 1, wn = wid & 1;
  const int l15 = lane & 15, lhi = lane >> 4;

  int aRow[4], aOff[4], bRow[4], bOff[4];
  #pragma unroll
  for (int j = 0; j < 4; j++){
    int c = j * 256 + tid;
    int i = c >> 3, op = c & 7;
    int o = op ^ (i & 7);
    int ie = min(i, rows - 1);
    aRow[j] = rowTok[row0 + ie];
    aOff[j] = o * 8;
    bRow[j] = n0 + i;
    bOff[j] = o * 8;
  }

  floatx4 acc[4][4] = {};
  constexpr int NT = KDIM / 64;

  for (int kt = 0; kt < NT; ++kt){
    #pragma unroll
    for (int j = 0; j < 4; j++)
      gload_lds16(A + (size_t)aRow[j] * KDIM + kt * 64 + aOff[j],
                  As + (j * 256 + tid) * 16);
    #pragma unroll
    for (int j = 0; j < 4; j++)
      gload_lds16(Bt + (size_t)bRow[j] * KDIM + kt * 64 + bOff[j],
                  Bs + (j * 256 + tid) * 16);
    __syncthreads();
    #pragma unroll
    for (int kk = 0; kk < 2; ++kk){
      short8 a[4], b[4];
      #pragma unroll
      for (int m = 0; m < 4; m++){
        int rr = wm * 64 + m * 16 + l15;
        a[m] = *reinterpret_cast<const short8*>(
            As + rr * 128 + ((kk * 64 + lhi * 16) ^ ((rr & 7) << 4)));
      }
      #pragma unroll
      for (int n = 0; n < 4; n++){
        int rr = wn * 64 + n * 16 + l15;
        b[n] = *reinterpret_cast<const short8*>(
            Bs + rr * 128 + ((kk * 64 + lhi * 16) ^ ((rr & 7) << 4)));
      }
      #pragma unroll
      for (int m = 0; m < 4; m++)
        #pragma unroll
        for (int n = 0; n < 4; n++)
          acc[m][n] = __builtin_amdgcn_mfma_f32_16x16x32_bf16(a[m], b[n], acc[m][n], 0, 0, 0);
    }
    __syncthreads();
  }

  #pragma unroll
  for (int m = 0; m < 4; m++){
    #pragma unroll
    for (int n = 0; n < 4; n++){
      int gcol = n0 + wn * 64 + n * 16 + l15;
      float bv = bias[gcol];
      #pragma unroll
      for (int q = 0; q < 4; q++){
        int ri = wm * 64 + m * 16 + lhi * 4 + q;
        if (ri < rows){
          float v = fmaxf(acc[m][n][q] + bv, 0.f);
          outB[(size_t)(row0 + ri) * NDIM + gcol] = f2b(v);
        }
      }
    }
  }
}

// ===== K4: GEMM2, 64x128 tile, dbuf 2-phase; out bf16 O = (acc+bias)*rowW =====
template<int BMT, int KDIM, int NDIM>
__global__ __launch_bounds__(256) void k_gemm2(const unsigned short* __restrict__ A,
                                               const unsigned short* __restrict__ BtE,
                                               const unsigned short* __restrict__ BtS,
                                               const float* __restrict__ biasE,
                                               const float* __restrict__ biasS,
                                               const float* __restrict__ rowW,
                                               const int* __restrict__ tiles,
                                               unsigned short* __restrict__ outB){
  const int tileId = blockIdx.x;
  const int rows = tiles[tileId*3+1];
  if (rows == 0) return;
  const int row0 = tiles[tileId*3];
  const int eid  = tiles[tileId*3+2];
  const unsigned short* Bt = (eid < 16) ? (BtE + (size_t)eid * NDIM * KDIM) : BtS;
  const float* bias = (eid < 16) ? (biasE + eid * NDIM) : biasS;
  const int n0 = blockIdx.y * 128;

  constexpr int MREP = BMT / 32;
  constexpr int AISS = BMT * 8 / 256;

  __shared__ __align__(16) unsigned short As[2][BMT * 64];
  __shared__ __align__(16) unsigned short Bs[2][128 * 64];

  const int tid = threadIdx.x;
  const int lane = tid & 63;
  const int wid = tid >> 6;
  const int wm = wid >> 1, wn = wid & 1;
  const int l15 = lane & 15, lhi = lane >> 4;

  int aRow[AISS], aOff[AISS];
  #pragma unroll
  for (int j = 0; j < AISS; j++){
    int c = j * 256 + tid;
    int i = c >> 3, op = c & 7;
    int o = op ^ (i & 7);
    int ie = min(i, rows - 1);
    aRow[j] = row0 + ie;
    aOff[j] = o * 8;
  }
  int bRow[4], bOff[4];
  #pragma unroll
  for (int j = 0; j < 4; j++){
    int c = j * 256 + tid;
    int i = c >> 3, op = c & 7;
    int o = op ^ (i & 7);
    bRow[j] = n0 + i;
    bOff[j] = o * 8;
  }

  auto STAGE = [&](int buf, int kt){
    #pragma unroll
    for (int j = 0; j < AISS; j++)
      gload_lds16(A + (size_t)aRow[j] * KDIM + kt * 64 + aOff[j],
                  (char*)&As[buf][0] + (j * 256 + tid) * 16);
    #pragma unroll
    for (int j = 0; j < 4; j++)
      gload_lds16(Bt + (size_t)bRow[j] * KDIM + kt * 64 + bOff[j],
                  (char*)&Bs[buf][0] + (j * 256 + tid) * 16);
  };

  floatx4 acc[MREP][4] = {};
  constexpr int NT = KDIM / 64;

  STAGE(0, 0);
  for (int kt = 0; kt < NT; ++kt){
    const int cur = kt & 1;
    if (kt + 1 < NT){
      STAGE(cur ^ 1, kt + 1);
      asm volatile("s_waitcnt vmcnt(6)" ::: "memory");
    } else {
      asm volatile("s_waitcnt vmcnt(0)" ::: "memory");
    }
    __builtin_amdgcn_s_barrier();
    asm volatile("" ::: "memory");
    #pragma unroll
    for (int kk = 0; kk < 2; ++kk){
      short8 a[MREP], b[4];
      #pragma unroll
      for (int m = 0; m < MREP; m++){
        int rr = wm * (BMT/2) + m * 16 + l15;
        a[m] = *reinterpret_cast<const short8*>(
            (char*)&As[cur][0] + rr * 128 + ((kk * 64 + lhi * 16) ^ ((rr & 7) << 4)));
      }
      #pragma unroll
      for (int n = 0; n < 4; n++){
        int rr = wn * 64 + n * 16 + l15;
        b[n] = *reinterpret_cast<const short8*>(
            (char*)&Bs[cur][0] + rr * 128 + ((kk * 64 + lhi * 16) ^ ((rr & 7) << 4)));
      }
      #pragma unroll
      for (int m = 0; m < MREP; m++)
        #pragma unroll
        for (int n = 0; n < 4; n++)
          acc[m][n] = __builtin_amdgcn_mfma_f32_16x16x32_bf16(a[m], b[n], acc[m][n], 0, 0, 0);
    }
    asm volatile("" ::: "memory");
    __builtin_amdgcn_s_barrier();
  }

  #pragma unroll
  for (int m = 0; m < MREP; m++){
    #pragma unroll
    for (int n = 0; n < 4; n++){
      int gcol = n0 + wn * 64 + n * 16 + l15;
      float bv = bias[gcol];
      #pragma unroll
      for (int q = 0; q < 4; q++){
        int ri = wm * (BMT/2) + m * 16 + lhi * 4 + q;
        if (ri < rows){
          float v = (acc[m][n][q] + bv) * rowW[row0 + ri];
          outB[(size_t)(row0 + ri) * NDIM + gcol] = f2b(v);
        }
      }
    }
  }
}

// ===== K5: combine y = O_dense + O_e0 + O_e1 (bf16 O, weights folded) =====
__global__ __launch_bounds__(256) void k_combine(const unsigned short* __restrict__ O,
                                                 const int* __restrict__ inv,
                                                 float* __restrict__ y){
  int q = blockIdx.x * 256 + threadIdx.x;
  int t = q >> 7, c4 = q & 127;
  const ushort4* O4 = reinterpret_cast<const ushort4*>(O);
  ushort4 d  = O4[(size_t)t * 128 + c4];
  int p0 = inv[2*t], p1 = inv[2*t+1];
  ushort4 o0 = O4[(size_t)(NTOK + p0) * 128 + c4];
  ushort4 o1 = O4[(size_t)(NTOK + p1) * 128 + c4];
  float4 r;
  r.x = b2f(d.x) + b2f(o0.x) + b2f(o1.x);
  r.y = b2f(d.y) + b2f(o0.y) + b2f(o1.y);
  r.z = b2f(d.z) + b2f(o0.z) + b2f(o1.z);
  r.w = b2f(d.w) + b2f(o0.w) + b2f(o1.w);
  reinterpret_cast<float4*>(y)[q] = r;
}

extern "C" void kernel_launch(void* const* d_in, const int* in_sizes, int n_in,
                              void* d_out, int out_size, void* d_ws, size_t ws_size,
                              hipStream_t stream){
  const float* x    = (const float*)d_in[0];
  const int*   opid = (const int*)d_in[1];
  const float* ekey = (const float*)d_in[2];
  const float* sW1  = (const float*)d_in[3];
  const float* sb1  = (const float*)d_in[4];
  const float* sW2  = (const float*)d_in[5];
  const float* sb2  = (const float*)d_in[6];
  const float* eW1  = (const float*)d_in[7];
  const float* eb1  = (const float*)d_in[8];
  const float* eW2  = (const float*)d_in[9];
  const float* eb2  = (const float*)d_in[10];
  const float* gate = (const float*)d_in[11];
  float* y = (float*)d_out;

  char* ws = (char*)d_ws;
  size_t off = 0;
  auto alloc = [&](size_t bytes) -> char* {
    char* p = ws + off; off += (bytes + 255) & ~(size_t)255; return p;
  };
  unsigned short* Xb   = (unsigned short*)alloc((size_t)NTOK * C_DIM * 2);
  unsigned short* sW1t = (unsigned short*)alloc((size_t)H_DIM * C_DIM * 2);
  unsigned short* sW2t = (unsigned short*)alloc((size_t)C_DIM * H_DIM * 2);
  unsigned short* eW1t = (unsigned short*)alloc((size_t)16 * H_DIM * C_DIM * 2);
  unsigned short* eW2t = (unsigned short*)alloc((size_t)16 * C_DIM * H_DIM * 2);
  unsigned short* H1   = (unsigned short*)alloc((size_t)NROWS * H_DIM * 2);
  unsigned short* O    = (unsigned short*)alloc((size_t)NROWS * C_DIM * 2);
  float* wv     = (float*)alloc((size_t)NSLOT * 4);
  int*   gids   = (int*)alloc((size_t)NSLOT * 4);
  int*   inv    = (int*)alloc((size_t)NSLOT * 4);
  int*   rowTok = (int*)alloc((size_t)NROWS * 4);
  float* rowW   = (float*)alloc((size_t)NROWS * 4);
  int*   tiles128 = (int*)alloc((size_t)MAXT128 * 3 * 4);
  int*   tiles64  = (int*)alloc((size_t)MAXT64 * 3 * 4);

  k_router<<<512, 256, 0, stream>>>(x, opid, ekey, Xb, gids, wv);
  k_sortw1<<<1 + 1088, 256, 0, stream>>>(gids, wv, gate, sW1, eW1, sW1t, eW1t,
                                         inv, rowTok, rowW, tiles128, tiles64);
  k_g1w2<<<NBG1 + 1088, 256, 0, stream>>>(Xb, eW1t, sW1t, eb1, sb1, rowTok, tiles128, H1,
                                          sW2, eW2, sW2t, eW2t);
  k_gemm2<64, H_DIM, C_DIM><<<dim3(MAXT64, C_DIM/128), 256, 0, stream>>>(
      H1, eW2t, sW2t, eb2, sb2, rowW, tiles64, O);
  k_combine<<<1024, 256, 0, stream>>>(O, inv, y);
}